// Round 3
// baseline (1522.285 us; speedup 1.0000x reference)
//
#include <hip/hip_runtime.h>

#define TLEN 512

__device__ __forceinline__ float sigmoidf_(float x) {
    return 1.0f / (1.0f + __expf(-x));
}
// tanh via exp, saturates correctly for large |x|
__device__ __forceinline__ float tanhf_(float x) {
    return 1.0f - 2.0f / (__expf(2.0f * x) + 1.0f);
}

// One wave = one batch element. lane = gh*32 + j.
//  gh=0 lanes own rows {j, j+32}    = (i_j, f_j)
//  gh=1 lanes own rows {j+64, j+96} = (g_j, o_j)
// of each of the 3 recurrent/input matrices (w_hh0, w_ih1, w_hh1),
// kept in VGPRs (192 floats/lane). h broadcast via per-wave LDS (no barriers).
// launch_bounds(256,1): allow up to 512 VGPRs so the 192 weight regs do NOT
// spill (R2's (256,2) capped at 128 VGPR -> ~100 scratch spills reloaded
// every timestep = 3x issue bloat).
__global__ __launch_bounds__(256, 1)
void lstm2_kernel(const float* __restrict__ x,
                  const float* __restrict__ w_ih0,
                  const float* __restrict__ w_hh0,
                  const float* __restrict__ b_ih0,
                  const float* __restrict__ b_hh0,
                  const float* __restrict__ w_ih1,
                  const float* __restrict__ w_hh1,
                  const float* __restrict__ b_ih1,
                  const float* __restrict__ b_hh1,
                  const float* __restrict__ fc1_w,
                  const float* __restrict__ fc1_b,
                  const float* __restrict__ fc2_w,
                  const float* __restrict__ fc2_b,
                  float* __restrict__ out)
{
    __shared__ float x_lds[4][TLEN];
    __shared__ float hb0[4][32];
    __shared__ float hb1[4][32];

    const int tid  = threadIdx.x;
    const int wid  = tid >> 6;
    const int lane = tid & 63;
    const int gh   = lane >> 5;   // gate-half: 0 -> (i,f), 1 -> (g,o)
    const int j    = lane & 31;   // hidden unit
    const long b   = (long)blockIdx.x * 4 + wid;

    // stage this wave's x sequence (wave-private LDS region, no barrier needed)
    for (int i = lane; i < TLEN; i += 64) x_lds[wid][i] = x[b * TLEN + i];
    if (lane < 32) { hb0[wid][lane] = 0.0f; hb1[wid][lane] = 0.0f; }

    const int r0 = j + 64 * gh;
    const int r1 = r0 + 32;

    // weights in registers: 6 rows of 32
    float w00[32], w01[32], w10[32], w11[32], w20[32], w21[32];
    #pragma unroll
    for (int q = 0; q < 8; ++q) {
        float4 v;
        v = *(const float4*)(w_hh0 + r0 * 32 + 4 * q);
        w00[4*q] = v.x; w00[4*q+1] = v.y; w00[4*q+2] = v.z; w00[4*q+3] = v.w;
        v = *(const float4*)(w_hh0 + r1 * 32 + 4 * q);
        w01[4*q] = v.x; w01[4*q+1] = v.y; w01[4*q+2] = v.z; w01[4*q+3] = v.w;
        v = *(const float4*)(w_ih1 + r0 * 32 + 4 * q);
        w10[4*q] = v.x; w10[4*q+1] = v.y; w10[4*q+2] = v.z; w10[4*q+3] = v.w;
        v = *(const float4*)(w_ih1 + r1 * 32 + 4 * q);
        w11[4*q] = v.x; w11[4*q+1] = v.y; w11[4*q+2] = v.z; w11[4*q+3] = v.w;
        v = *(const float4*)(w_hh1 + r0 * 32 + 4 * q);
        w20[4*q] = v.x; w20[4*q+1] = v.y; w20[4*q+2] = v.z; w20[4*q+3] = v.w;
        v = *(const float4*)(w_hh1 + r1 * 32 + 4 * q);
        w21[4*q] = v.x; w21[4*q+1] = v.y; w21[4*q+2] = v.z; w21[4*q+3] = v.w;
    }

    const float xw0  = w_ih0[r0];
    const float xw1  = w_ih0[r1];
    const float bb00 = b_ih0[r0] + b_hh0[r0];
    const float bb01 = b_ih0[r1] + b_hh0[r1];
    const float bb10 = b_ih1[r0] + b_hh1[r0];
    const float bb11 = b_ih1[r1] + b_hh1[r1];

    const float ghf = (float)gh;          // 0.0 or 1.0
    const float sc  = 1.0f + ghf;         // 1 or 2 (tanh-via-sigmoid trick)

    float c0 = 0.0f, c1 = 0.0f;

    for (int t = 0; t < TLEN; ++t) {
        const float xt = x_lds[wid][t];
        float a00 = bb00 + xt * xw0;      // layer0 gate rows r0/r1
        float a01 = bb01 + xt * xw1;
        float a10 = 0.0f, a11 = 0.0f;     // w_hh1 . h1_prev part

        #pragma unroll
        for (int q = 0; q < 8; ++q) {
            float4 h0v = *(const float4*)&hb0[wid][4 * q];
            float4 h1v = *(const float4*)&hb1[wid][4 * q];
            a00 += w00[4*q]*h0v.x + w00[4*q+1]*h0v.y + w00[4*q+2]*h0v.z + w00[4*q+3]*h0v.w;
            a01 += w01[4*q]*h0v.x + w01[4*q+1]*h0v.y + w01[4*q+2]*h0v.z + w01[4*q+3]*h0v.w;
            a10 += w20[4*q]*h1v.x + w20[4*q+1]*h1v.y + w20[4*q+2]*h1v.z + w20[4*q+3]*h1v.w;
            a11 += w21[4*q]*h1v.x + w21[4*q+1]*h1v.y + w21[4*q+2]*h1v.z + w21[4*q+3]*h1v.w;
        }

        // ---- layer0 nonlinearity (branchless gate-type select) ----
        {
            float s  = sigmoidf_(a00 * sc);
            float v0 = s * sc - ghf;            // gh? tanh(a00) : sigmoid(a00)
            float v1 = sigmoidf_(a01);          // f (gh0) or o (gh1)
            float ov0 = __shfl_xor(v0, 32);
            float ov1 = __shfl_xor(v1, 32);
            float i_ = gh ? ov0 : v0;
            float f_ = gh ? ov1 : v1;
            float g_ = gh ? v0 : ov0;
            float o_ = gh ? v1 : ov1;
            c0 = f_ * c0 + i_ * g_;
            float h0 = o_ * tanhf_(c0);
            hb0[wid][j] = h0;                   // lanes j and j+32 write same value
        }

        // ---- layer1: w_ih1 . h0_new + (w_hh1 . h1_prev) ----
        float a10b = bb10 + a10;
        float a11b = bb11 + a11;
        #pragma unroll
        for (int q = 0; q < 8; ++q) {
            float4 hv = *(const float4*)&hb0[wid][4 * q];
            a10b += w10[4*q]*hv.x + w10[4*q+1]*hv.y + w10[4*q+2]*hv.z + w10[4*q+3]*hv.w;
            a11b += w11[4*q]*hv.x + w11[4*q+1]*hv.y + w11[4*q+2]*hv.z + w11[4*q+3]*hv.w;
        }
        {
            float s  = sigmoidf_(a10b * sc);
            float v0 = s * sc - ghf;
            float v1 = sigmoidf_(a11b);
            float ov0 = __shfl_xor(v0, 32);
            float ov1 = __shfl_xor(v1, 32);
            float i_ = gh ? ov0 : v0;
            float f_ = gh ? ov1 : v1;
            float g_ = gh ? v0 : ov0;
            float o_ = gh ? v1 : ov1;
            c1 = f_ * c1 + i_ * g_;
            float h1 = o_ * tanhf_(c1);
            hb1[wid][j] = h1;
        }
    }

    // ---- head: out[b] = fc2( relu( fc1 . h1_T ) ) ----
    {
        const int r = lane & 15;
        float acc = fc1_b[r];
        #pragma unroll
        for (int q = 0; q < 8; ++q) {
            float4 wv = *(const float4*)(fc1_w + r * 32 + 4 * q);
            float4 hv = *(const float4*)&hb1[wid][4 * q];
            acc += wv.x * hv.x + wv.y * hv.y + wv.z * hv.z + wv.w * hv.w;
        }
        acc = fmaxf(acc, 0.0f) * fc2_w[r];
        acc = (lane < 16) ? acc : 0.0f;
        acc += __shfl_xor(acc, 8);
        acc += __shfl_xor(acc, 4);
        acc += __shfl_xor(acc, 2);
        acc += __shfl_xor(acc, 1);
        if (lane == 0) out[b] = acc + fc2_b[0];
    }
}

extern "C" void kernel_launch(void* const* d_in, const int* in_sizes, int n_in,
                              void* d_out, int out_size, void* d_ws, size_t ws_size,
                              hipStream_t stream) {
    const float* x     = (const float*)d_in[0];
    const float* w_ih0 = (const float*)d_in[1];
    const float* w_hh0 = (const float*)d_in[2];
    const float* b_ih0 = (const float*)d_in[3];
    const float* b_hh0 = (const float*)d_in[4];
    const float* w_ih1 = (const float*)d_in[5];
    const float* w_hh1 = (const float*)d_in[6];
    const float* b_ih1 = (const float*)d_in[7];
    const float* b_hh1 = (const float*)d_in[8];
    const float* fc1_w = (const float*)d_in[9];
    const float* fc1_b = (const float*)d_in[10];
    const float* fc2_w = (const float*)d_in[11];
    const float* fc2_b = (const float*)d_in[12];
    float* out = (float*)d_out;

    const int B = 4096;
    dim3 grid(B / 4);     // 4 independent waves (batch elements) per block
    dim3 block(256);
    hipLaunchKernelGGL(lstm2_kernel, grid, block, 0, stream,
                       x, w_ih0, w_hh0, b_ih0, b_hh0,
                       w_ih1, w_hh1, b_ih1, b_hh1,
                       fc1_w, fc1_b, fc2_w, fc2_b, out);
}

// Round 4
// 499.207 us; speedup vs baseline: 3.0494x; 3.0494x over previous
//
#include <hip/hip_runtime.h>

#define TLEN 512
#define XSTR 516      // x LDS row stride (floats): %4==0 for float4 stores
#define HSTR 40       // h LDS row stride (bf16 elems): 80B rows, 16B-aligned frags

typedef __attribute__((ext_vector_type(8))) short bf16x8;
typedef __attribute__((ext_vector_type(4))) float f32x4;

__device__ __forceinline__ float sigmoidf_(float x) {
    return 1.0f / (1.0f + __expf(-x));
}
__device__ __forceinline__ float tanhf_(float x) {
    return 1.0f - 2.0f / (__expf(2.0f * x) + 1.0f);
}
// bf16 RNE convert via bit ops (no hip_bf16 API dependence)
__device__ __forceinline__ unsigned short f2bf(float f) {
    unsigned u = __float_as_uint(f);
    u += 0x7FFFu + ((u >> 16) & 1u);
    return (unsigned short)(u >> 16);
}
__device__ __forceinline__ float bf2f(unsigned short b) {
    return __uint_as_float(((unsigned)b) << 16);
}

// Block = 16 batch elements, 4 waves.
//  W0/W1: layer0, gate-half jbase=0/16, computes h0[t]      (t = 0..511)
//  W2/W3: layer1, gate-half jbase=0/16, computes h1[t-1]    (t = 1..512)
// One barrier per step; h0/h1 exchanged as bf16 hi+lo planes in LDS (dbuf).
// MFMA: D[16g x 16b] = Wtile[16g x 32k] @ h[32k x 16b], fp32-accurate via
// bf16 hi/lo split: Whi*hhi + Whi*hlo + Wlo*hhi (3 MFMAs per tile).
__global__ __launch_bounds__(256, 1)
void lstm2_mfma(const float* __restrict__ x,
                const float* __restrict__ w_ih0,
                const float* __restrict__ w_hh0,
                const float* __restrict__ b_ih0,
                const float* __restrict__ b_hh0,
                const float* __restrict__ w_ih1,
                const float* __restrict__ w_hh1,
                const float* __restrict__ b_ih1,
                const float* __restrict__ b_hh1,
                const float* __restrict__ fc1_w,
                const float* __restrict__ fc1_b,
                const float* __restrict__ fc2_w,
                const float* __restrict__ fc2_b,
                float* __restrict__ out)
{
    __shared__ float x_lds[16][XSTR];
    __shared__ unsigned short h0b[2][2][16][HSTR];  // [dbuf][hi/lo][b][k]
    __shared__ unsigned short h1b[2][2][16][HSTR];
    __shared__ float h1f[16][36];                   // final h1 (f32) for head

    const int tid  = threadIdx.x;
    const int wid  = tid >> 6;
    const int lane = tid & 63;
    const int col  = lane & 15;   // batch col (N) == weight-row-in-tile (A)
    const int kq   = lane >> 4;   // k-quad: frag k0 = kq*8; D rows = kq*4+r
    const int b0   = blockIdx.x * 16;

    // ---- stage x[b0..b0+15][0..511] into LDS (coalesced float4) ----
    for (int i4 = tid; i4 < (16 * TLEN) / 4; i4 += 256) {
        const int idx = i4 * 4;
        const int row = idx >> 9, cx = idx & 511;
        float4 v = *(const float4*)(x + (long)(b0 + row) * TLEN + cx);
        *(float4*)&x_lds[row][cx] = v;
    }
    // zero h double-buffers (both planes)
    for (int i = tid; i < 2 * 2 * 16 * HSTR; i += 256) {
        ((unsigned short*)h0b)[i] = 0;
        ((unsigned short*)h1b)[i] = 0;
    }

    const bool L0   = (wid < 2);
    const int jbase = (wid & 1) * 16;

    // ---- weight fragments (A-operand), bf16 hi+lo, in registers ----
    // tile q covers gate rows [jbase + 32q, jbase + 32q + 16)  (q: i,f,g,o)
    // A-frag: lane holds W[rb + col][kq*8 + e], e=0..7
    bf16x8 wAhi[4], wAlo[4];   // L0: w_hh0 ; L1: w_ih1
    bf16x8 wBhi[4], wBlo[4];   // L1 only: w_hh1
    f32x4 bias[4];             // bias[q][r] for D row = jbase+32q + kq*4+r
    f32x4 xw;                  // L0 only: w_ih0 col for this lane's D rows
    f32x4 xwq[4];

    const float* WA = L0 ? w_hh0 : w_ih1;
    #pragma unroll
    for (int q = 0; q < 4; ++q) {
        const int rb = jbase + 32 * q;
        const int arow = rb + col;
        const int k0 = kq * 8;
        #pragma unroll
        for (int e = 0; e < 8; ++e) {
            const float w = WA[arow * 32 + k0 + e];
            const unsigned short hb = f2bf(w);
            wAhi[q][e] = (short)hb;
            wAlo[q][e] = (short)f2bf(w - bf2f(hb));
        }
        if (!L0) {
            #pragma unroll
            for (int e = 0; e < 8; ++e) {
                const float w = w_hh1[arow * 32 + k0 + e];
                const unsigned short hb = f2bf(w);
                wBhi[q][e] = (short)hb;
                wBlo[q][e] = (short)f2bf(w - bf2f(hb));
            }
        }
        #pragma unroll
        for (int r = 0; r < 4; ++r) {
            const int rowr = rb + kq * 4 + r;
            bias[q][r] = L0 ? (b_ih0[rowr] + b_hh0[rowr])
                            : (b_ih1[rowr] + b_hh1[rowr]);
            xwq[q][r] = L0 ? w_ih0[rowr] : 0.0f;
        }
    }
    (void)xw;

    float c_[4] = {0.0f, 0.0f, 0.0f, 0.0f};   // cell state (4 j's, 1 batch col)
    __syncthreads();

    for (int t = 0; t <= TLEN; ++t) {
        const int cur = t & 1;
        const int prv = (t + 1) & 1;

        if (L0) {
            if (t < TLEN) {
                // h0_prev B-frags
                const bf16x8 bhi = *(const bf16x8*)&h0b[prv][0][col][kq * 8];
                const bf16x8 blo = *(const bf16x8*)&h0b[prv][1][col][kq * 8];
                const float xt = x_lds[col][t];
                f32x4 acc[4];
                #pragma unroll
                for (int q = 0; q < 4; ++q) acc[q] = bias[q] + xwq[q] * xt;
                #pragma unroll
                for (int q = 0; q < 4; ++q) {
                    acc[q] = __builtin_amdgcn_mfma_f32_16x16x32_bf16(wAhi[q], bhi, acc[q], 0, 0, 0);
                    acc[q] = __builtin_amdgcn_mfma_f32_16x16x32_bf16(wAhi[q], blo, acc[q], 0, 0, 0);
                    acc[q] = __builtin_amdgcn_mfma_f32_16x16x32_bf16(wAlo[q], bhi, acc[q], 0, 0, 0);
                }
                unsigned short hbs[4], lbs[4];
                #pragma unroll
                for (int r = 0; r < 4; ++r) {
                    const float iv = sigmoidf_(acc[0][r]);
                    const float fv = sigmoidf_(acc[1][r]);
                    const float gv = tanhf_(acc[2][r]);
                    const float ov = sigmoidf_(acc[3][r]);
                    c_[r] = fv * c_[r] + iv * gv;
                    const float hv = ov * tanhf_(c_[r]);
                    hbs[r] = f2bf(hv);
                    lbs[r] = f2bf(hv - bf2f(hbs[r]));
                }
                uint2 hw, lw;
                hw.x = (unsigned)hbs[0] | ((unsigned)hbs[1] << 16);
                hw.y = (unsigned)hbs[2] | ((unsigned)hbs[3] << 16);
                lw.x = (unsigned)lbs[0] | ((unsigned)lbs[1] << 16);
                lw.y = (unsigned)lbs[2] | ((unsigned)lbs[3] << 16);
                *(uint2*)&h0b[cur][0][col][jbase + kq * 4] = hw;
                *(uint2*)&h0b[cur][1][col][jbase + kq * 4] = lw;
            }
        } else {
            if (t >= 1) {
                // computing h1[s], s = t-1: h0[s] in h0b[prv], h1[s-1] in h1b[cur]
                const bf16x8 a0hi = *(const bf16x8*)&h0b[prv][0][col][kq * 8];
                const bf16x8 a0lo = *(const bf16x8*)&h0b[prv][1][col][kq * 8];
                const bf16x8 a1hi = *(const bf16x8*)&h1b[cur][0][col][kq * 8];
                const bf16x8 a1lo = *(const bf16x8*)&h1b[cur][1][col][kq * 8];
                f32x4 acc[4];
                #pragma unroll
                for (int q = 0; q < 4; ++q) acc[q] = bias[q];
                #pragma unroll
                for (int q = 0; q < 4; ++q) {
                    acc[q] = __builtin_amdgcn_mfma_f32_16x16x32_bf16(wAhi[q], a0hi, acc[q], 0, 0, 0);
                    acc[q] = __builtin_amdgcn_mfma_f32_16x16x32_bf16(wAhi[q], a0lo, acc[q], 0, 0, 0);
                    acc[q] = __builtin_amdgcn_mfma_f32_16x16x32_bf16(wAlo[q], a0hi, acc[q], 0, 0, 0);
                    acc[q] = __builtin_amdgcn_mfma_f32_16x16x32_bf16(wBhi[q], a1hi, acc[q], 0, 0, 0);
                    acc[q] = __builtin_amdgcn_mfma_f32_16x16x32_bf16(wBhi[q], a1lo, acc[q], 0, 0, 0);
                    acc[q] = __builtin_amdgcn_mfma_f32_16x16x32_bf16(wBlo[q], a1hi, acc[q], 0, 0, 0);
                }
                unsigned short hbs[4], lbs[4];
                float hvf[4];
                #pragma unroll
                for (int r = 0; r < 4; ++r) {
                    const float iv = sigmoidf_(acc[0][r]);
                    const float fv = sigmoidf_(acc[1][r]);
                    const float gv = tanhf_(acc[2][r]);
                    const float ov = sigmoidf_(acc[3][r]);
                    c_[r] = fv * c_[r] + iv * gv;
                    const float hv = ov * tanhf_(c_[r]);
                    hvf[r] = hv;
                    hbs[r] = f2bf(hv);
                    lbs[r] = f2bf(hv - bf2f(hbs[r]));
                }
                uint2 hw, lw;
                hw.x = (unsigned)hbs[0] | ((unsigned)hbs[1] << 16);
                hw.y = (unsigned)hbs[2] | ((unsigned)hbs[3] << 16);
                lw.x = (unsigned)lbs[0] | ((unsigned)lbs[1] << 16);
                lw.y = (unsigned)lbs[2] | ((unsigned)lbs[3] << 16);
                *(uint2*)&h1b[prv][0][col][jbase + kq * 4] = hw;
                *(uint2*)&h1b[prv][1][col][jbase + kq * 4] = lw;
                if (t == TLEN) {
                    float4 hv4 = make_float4(hvf[0], hvf[1], hvf[2], hvf[3]);
                    *(float4*)&h1f[col][jbase + kq * 4] = hv4;
                }
            }
        }
        __syncthreads();
    }

    // ---- head: out[b] = fc2( relu( fc1 . h1_T ) ) + fc2_b, by wave 0 ----
    if (wid == 0) {
        float s = 0.0f;
        #pragma unroll
        for (int it = 0; it < 4; ++it) {
            const int r = kq * 4 + it;    // fc1 row in [0,16)
            float acc = fc1_b[r];
            #pragma unroll
            for (int qq = 0; qq < 8; ++qq) {
                const float4 wv = *(const float4*)(fc1_w + r * 32 + qq * 4);
                const float4 hv = *(const float4*)&h1f[col][qq * 4];
                acc += wv.x * hv.x + wv.y * hv.y + wv.z * hv.z + wv.w * hv.w;
            }
            s += fmaxf(acc, 0.0f) * fc2_w[r];
        }
        s += __shfl_xor(s, 16);
        s += __shfl_xor(s, 32);
        if (lane < 16) out[b0 + col] = s + fc2_b[0];
    }
}

extern "C" void kernel_launch(void* const* d_in, const int* in_sizes, int n_in,
                              void* d_out, int out_size, void* d_ws, size_t ws_size,
                              hipStream_t stream) {
    const float* x     = (const float*)d_in[0];
    const float* w_ih0 = (const float*)d_in[1];
    const float* w_hh0 = (const float*)d_in[2];
    const float* b_ih0 = (const float*)d_in[3];
    const float* b_hh0 = (const float*)d_in[4];
    const float* w_ih1 = (const float*)d_in[5];
    const float* w_hh1 = (const float*)d_in[6];
    const float* b_ih1 = (const float*)d_in[7];
    const float* b_hh1 = (const float*)d_in[8];
    const float* fc1_w = (const float*)d_in[9];
    const float* fc1_b = (const float*)d_in[10];
    const float* fc2_w = (const float*)d_in[11];
    const float* fc2_b = (const float*)d_in[12];
    float* out = (float*)d_out;

    dim3 grid(4096 / 16);   // 256 blocks = 1 per CU
    dim3 block(256);        // 4 waves
    hipLaunchKernelGGL(lstm2_mfma, grid, block, 0, stream,
                       x, w_ih0, w_hh0, b_ih0, b_hh0,
                       w_ih1, w_hh1, b_ih1, b_hh1,
                       fc1_w, fc1_b, fc2_w, fc2_b, out);
}

// Round 5
// 438.138 us; speedup vs baseline: 3.4744x; 1.1394x over previous
//
#include <hip/hip_runtime.h>

#define TLEN 512
#define XSTR 516      // x LDS row stride (floats)
#define HSTR 40       // h LDS row stride (bf16 elems): 80B rows, 16B-aligned frags

typedef __attribute__((ext_vector_type(8))) short bf16x8;
typedef __attribute__((ext_vector_type(4))) float f32x4;

__device__ __forceinline__ float sigmoidf_(float x) {
    return 1.0f / (1.0f + __expf(-x));
}
__device__ __forceinline__ float tanhf_(float x) {
    return 1.0f - 2.0f / (__expf(2.0f * x) + 1.0f);
}
__device__ __forceinline__ unsigned short f2bf(float f) {   // RNE
    unsigned u = __float_as_uint(f);
    u += 0x7FFFu + ((u >> 16) & 1u);
    return (unsigned short)(u >> 16);
}
__device__ __forceinline__ float bf2f(unsigned short b) {
    return __uint_as_float(((unsigned)b) << 16);
}

// Block = 16 batch cols, 8 waves (512 thr).
//  W0-3: layer0, tiles {2w, 2w+1};  W4-7: layer1 (lagged 1 step), same tiles.
// MIXED-GATE tiles: tile q (q=0..7) covers j in [4q, 4q+4); tile-row = 4*jj + g
// (g = gate i/f/g/o). Lane (col=lane&15, kq=lane>>4) gets D rows kq*4+r =
// all 4 gates of j = 4*tile + kq  -> NL is fully lane-local with 2 tiles/wave.
// A-frag row for lane = col -> weight row = (col&3)*32 + 4*tile + (col>>2).
// fp32 accuracy: bf16 hi/lo split, Whi*hhi + Whi*hlo + Wlo*hhi (3 MFMAs/tile).
__global__ __launch_bounds__(512, 1)
void lstm2_mfma(const float* __restrict__ x,
                const float* __restrict__ w_ih0,
                const float* __restrict__ w_hh0,
                const float* __restrict__ b_ih0,
                const float* __restrict__ b_hh0,
                const float* __restrict__ w_ih1,
                const float* __restrict__ w_hh1,
                const float* __restrict__ b_ih1,
                const float* __restrict__ b_hh1,
                const float* __restrict__ fc1_w,
                const float* __restrict__ fc1_b,
                const float* __restrict__ fc2_w,
                const float* __restrict__ fc2_b,
                float* __restrict__ out)
{
    __shared__ float x_lds[16][XSTR];
    __shared__ unsigned short h0b[2][2][16][HSTR];  // [dbuf][hi/lo][b][k]
    __shared__ unsigned short h1b[2][2][16][HSTR];
    __shared__ float h1f[16][36];                   // final h1 (f32) for head

    const int tid  = threadIdx.x;
    const int wid  = tid >> 6;
    const int lane = tid & 63;
    const int col  = lane & 15;   // batch col
    const int kq   = lane >> 4;
    const int b0   = blockIdx.x * 16;

    // ---- stage x (coalesced float4) ----
    for (int i4 = tid; i4 < (16 * TLEN) / 4; i4 += 512) {
        const int idx = i4 * 4;
        const int row = idx >> 9, cx = idx & 511;
        float4 v = *(const float4*)(x + (long)(b0 + row) * TLEN + cx);
        *(float4*)&x_lds[row][cx] = v;
    }
    for (int i = tid; i < 2 * 2 * 16 * HSTR; i += 512) {
        ((unsigned short*)h0b)[i] = 0;
        ((unsigned short*)h1b)[i] = 0;
    }

    const bool L0   = (wid < 4);
    const int  w4   = wid & 3;
    const int  tile0 = 2 * w4;
    const int  tile1 = 2 * w4 + 1;
    const int  j0   = 4 * tile0 + kq;      // this lane's j for tile0
    const int  j1   = 4 * tile1 + kq;
    const int  k0   = kq * 8;

    // A-frag weight rows (mixed-gate tile ordering)
    const int arow0 = (col & 3) * 32 + 4 * tile0 + (col >> 2);
    const int arow1 = (col & 3) * 32 + 4 * tile1 + (col >> 2);

    const float* WA = L0 ? w_hh0 : w_ih1;
    bf16x8 wA0hi, wA0lo, wA1hi, wA1lo;
    bf16x8 wB0hi, wB0lo, wB1hi, wB1lo;
    #pragma unroll
    for (int e = 0; e < 8; ++e) {
        float w;
        unsigned short hb;
        w = WA[arow0 * 32 + k0 + e]; hb = f2bf(w);
        wA0hi[e] = (short)hb; wA0lo[e] = (short)f2bf(w - bf2f(hb));
        w = WA[arow1 * 32 + k0 + e]; hb = f2bf(w);
        wA1hi[e] = (short)hb; wA1lo[e] = (short)f2bf(w - bf2f(hb));
        w = L0 ? 0.0f : w_hh1[arow0 * 32 + k0 + e]; hb = f2bf(w);
        wB0hi[e] = (short)hb; wB0lo[e] = (short)f2bf(w - bf2f(hb));
        w = L0 ? 0.0f : w_hh1[arow1 * 32 + k0 + e]; hb = f2bf(w);
        wB1hi[e] = (short)hb; wB1lo[e] = (short)f2bf(w - bf2f(hb));
    }

    // bias / x-weight for this lane's D rows: row(r) = r*32 + 4*tile + kq
    f32x4 bias0, bias1, xw0v, xw1v;
    #pragma unroll
    for (int r = 0; r < 4; ++r) {
        const int r0 = r * 32 + 4 * tile0 + kq;
        const int r1 = r * 32 + 4 * tile1 + kq;
        bias0[r] = L0 ? (b_ih0[r0] + b_hh0[r0]) : (b_ih1[r0] + b_hh1[r0]);
        bias1[r] = L0 ? (b_ih0[r1] + b_hh0[r1]) : (b_ih1[r1] + b_hh1[r1]);
        xw0v[r]  = L0 ? w_ih0[r0] : 0.0f;
        xw1v[r]  = L0 ? w_ih0[r1] : 0.0f;
    }

    float c0_ = 0.0f, c1_ = 0.0f;     // cell state for j0, j1 (one batch col)
    __syncthreads();

    for (int t = 0; t <= TLEN; ++t) {
        const int cur = t & 1;
        const int prv = cur ^ 1;

        if (L0) {
            if (t < TLEN) {
                const bf16x8 bhi = *(const bf16x8*)&h0b[prv][0][col][k0];
                const bf16x8 blo = *(const bf16x8*)&h0b[prv][1][col][k0];
                const float  xt  = x_lds[col][t];
                f32x4 a0 = bias0 + xw0v * xt;
                f32x4 a1 = bias1 + xw1v * xt;
                a0 = __builtin_amdgcn_mfma_f32_16x16x32_bf16(wA0hi, bhi, a0, 0, 0, 0);
                a1 = __builtin_amdgcn_mfma_f32_16x16x32_bf16(wA1hi, bhi, a1, 0, 0, 0);
                a0 = __builtin_amdgcn_mfma_f32_16x16x32_bf16(wA0hi, blo, a0, 0, 0, 0);
                a1 = __builtin_amdgcn_mfma_f32_16x16x32_bf16(wA1hi, blo, a1, 0, 0, 0);
                a0 = __builtin_amdgcn_mfma_f32_16x16x32_bf16(wA0lo, bhi, a0, 0, 0, 0);
                a1 = __builtin_amdgcn_mfma_f32_16x16x32_bf16(wA1lo, bhi, a1, 0, 0, 0);
                // NL, lane-local (all 4 gates of j0 / j1 in-register)
                {
                    const float iv = sigmoidf_(a0[0]), fv = sigmoidf_(a0[1]);
                    const float gv = tanhf_(a0[2]),    ov = sigmoidf_(a0[3]);
                    c0_ = fv * c0_ + iv * gv;
                    const float hv = ov * tanhf_(c0_);
                    const unsigned short hi = (unsigned short)(__float_as_uint(hv) >> 16); // trunc
                    h0b[cur][0][col][j0] = hi;
                    h0b[cur][1][col][j0] = f2bf(hv - bf2f(hi));
                }
                {
                    const float iv = sigmoidf_(a1[0]), fv = sigmoidf_(a1[1]);
                    const float gv = tanhf_(a1[2]),    ov = sigmoidf_(a1[3]);
                    c1_ = fv * c1_ + iv * gv;
                    const float hv = ov * tanhf_(c1_);
                    const unsigned short hi = (unsigned short)(__float_as_uint(hv) >> 16);
                    h0b[cur][0][col][j1] = hi;
                    h0b[cur][1][col][j1] = f2bf(hv - bf2f(hi));
                }
            }
        } else {
            if (t >= 1) {
                // computing h1[s], s=t-1: h0[s] in h0b[prv], h1[s-1] in h1b[cur]
                const bf16x8 a0hi = *(const bf16x8*)&h0b[prv][0][col][k0];
                const bf16x8 a0lo = *(const bf16x8*)&h0b[prv][1][col][k0];
                const bf16x8 a1hi = *(const bf16x8*)&h1b[cur][0][col][k0];
                const bf16x8 a1lo = *(const bf16x8*)&h1b[cur][1][col][k0];
                f32x4 a0 = bias0;
                f32x4 a1 = bias1;
                a0 = __builtin_amdgcn_mfma_f32_16x16x32_bf16(wA0hi, a0hi, a0, 0, 0, 0);
                a1 = __builtin_amdgcn_mfma_f32_16x16x32_bf16(wA1hi, a0hi, a1, 0, 0, 0);
                a0 = __builtin_amdgcn_mfma_f32_16x16x32_bf16(wA0hi, a0lo, a0, 0, 0, 0);
                a1 = __builtin_amdgcn_mfma_f32_16x16x32_bf16(wA1hi, a0lo, a1, 0, 0, 0);
                a0 = __builtin_amdgcn_mfma_f32_16x16x32_bf16(wA0lo, a0hi, a0, 0, 0, 0);
                a1 = __builtin_amdgcn_mfma_f32_16x16x32_bf16(wA1lo, a0hi, a1, 0, 0, 0);
                a0 = __builtin_amdgcn_mfma_f32_16x16x32_bf16(wB0hi, a1hi, a0, 0, 0, 0);
                a1 = __builtin_amdgcn_mfma_f32_16x16x32_bf16(wB1hi, a1hi, a1, 0, 0, 0);
                a0 = __builtin_amdgcn_mfma_f32_16x16x32_bf16(wB0hi, a1lo, a0, 0, 0, 0);
                a1 = __builtin_amdgcn_mfma_f32_16x16x32_bf16(wB1hi, a1lo, a1, 0, 0, 0);
                a0 = __builtin_amdgcn_mfma_f32_16x16x32_bf16(wB0lo, a1hi, a0, 0, 0, 0);
                a1 = __builtin_amdgcn_mfma_f32_16x16x32_bf16(wB1lo, a1hi, a1, 0, 0, 0);
                float hv0f, hv1f;
                {
                    const float iv = sigmoidf_(a0[0]), fv = sigmoidf_(a0[1]);
                    const float gv = tanhf_(a0[2]),    ov = sigmoidf_(a0[3]);
                    c0_ = fv * c0_ + iv * gv;
                    const float hv = ov * tanhf_(c0_);
                    hv0f = hv;
                    const unsigned short hi = (unsigned short)(__float_as_uint(hv) >> 16);
                    h1b[prv][0][col][j0] = hi;
                    h1b[prv][1][col][j0] = f2bf(hv - bf2f(hi));
                }
                {
                    const float iv = sigmoidf_(a1[0]), fv = sigmoidf_(a1[1]);
                    const float gv = tanhf_(a1[2]),    ov = sigmoidf_(a1[3]);
                    c1_ = fv * c1_ + iv * gv;
                    const float hv = ov * tanhf_(c1_);
                    hv1f = hv;
                    const unsigned short hi = (unsigned short)(__float_as_uint(hv) >> 16);
                    h1b[prv][0][col][j1] = hi;
                    h1b[prv][1][col][j1] = f2bf(hv - bf2f(hi));
                }
                if (t == TLEN) {
                    h1f[col][j0] = hv0f;
                    h1f[col][j1] = hv1f;
                }
            }
        }
        __syncthreads();
    }

    // ---- head: out[b] = fc2( relu( fc1 . h1_T ) ) + fc2_b, by wave 0 ----
    if (wid == 0) {
        float s = 0.0f;
        #pragma unroll
        for (int it = 0; it < 4; ++it) {
            const int r = kq * 4 + it;    // fc1 row in [0,16)
            float acc = fc1_b[r];
            #pragma unroll
            for (int qq = 0; qq < 8; ++qq) {
                const float4 wv = *(const float4*)(fc1_w + r * 32 + qq * 4);
                const float4 hv = *(const float4*)&h1f[col][qq * 4];
                acc += wv.x * hv.x + wv.y * hv.y + wv.z * hv.z + wv.w * hv.w;
            }
            s += fmaxf(acc, 0.0f) * fc2_w[r];
        }
        s += __shfl_xor(s, 16);
        s += __shfl_xor(s, 32);
        if (lane < 16) out[b0 + col] = s + fc2_b[0];
    }
}

extern "C" void kernel_launch(void* const* d_in, const int* in_sizes, int n_in,
                              void* d_out, int out_size, void* d_ws, size_t ws_size,
                              hipStream_t stream) {
    const float* x     = (const float*)d_in[0];
    const float* w_ih0 = (const float*)d_in[1];
    const float* w_hh0 = (const float*)d_in[2];
    const float* b_ih0 = (const float*)d_in[3];
    const float* b_hh0 = (const float*)d_in[4];
    const float* w_ih1 = (const float*)d_in[5];
    const float* w_hh1 = (const float*)d_in[6];
    const float* b_ih1 = (const float*)d_in[7];
    const float* b_hh1 = (const float*)d_in[8];
    const float* fc1_w = (const float*)d_in[9];
    const float* fc1_b = (const float*)d_in[10];
    const float* fc2_w = (const float*)d_in[11];
    const float* fc2_b = (const float*)d_in[12];
    float* out = (float*)d_out;

    dim3 grid(4096 / 16);   // 256 blocks, 1 per CU
    dim3 block(512);        // 8 waves -> 2 per SIMD
    hipLaunchKernelGGL(lstm2_mfma, grid, block, 0, stream,
                       x, w_ih0, w_hh0, b_ih0, b_hh0,
                       w_ih1, w_hh1, b_ih1, b_hh1,
                       fc1_w, fc1_b, fc2_w, fc2_b, out);
}

// Round 6
// 247.123 us; speedup vs baseline: 6.1600x; 1.7730x over previous
//
#include <hip/hip_runtime.h>

#define TLEN 512
#define XSTR 516      // x LDS row stride (floats)
#define HSTR 40       // h LDS row stride (bf16 elems): 80B rows, 16B-aligned frags

typedef __attribute__((ext_vector_type(8))) short bf16x8;
typedef __attribute__((ext_vector_type(4))) float f32x4;

#define LOG2E_ 1.44269504f

__device__ __forceinline__ float fexp2_(float x) {
#if __has_builtin(__builtin_amdgcn_exp2f)
    return __builtin_amdgcn_exp2f(x);      // raw v_exp_f32
#else
    return __expf(x * 0.69314718056f);
#endif
}
__device__ __forceinline__ float frcp_(float x) {
#if __has_builtin(__builtin_amdgcn_rcpf)
    return __builtin_amdgcn_rcpf(x);       // raw v_rcp_f32 (~1 ulp)
#else
    return 1.0f / x;
#endif
}
__device__ __forceinline__ float sigmoidf_(float x) {
    return frcp_(1.0f + fexp2_(-LOG2E_ * x));
}
__device__ __forceinline__ float tanhf_(float x) {
    return 1.0f - 2.0f * frcp_(1.0f + fexp2_((2.0f * LOG2E_) * x));
}
__device__ __forceinline__ unsigned short f2bf(float f) {   // RNE (setup only)
    unsigned u = __float_as_uint(f);
    u += 0x7FFFu + ((u >> 16) & 1u);
    return (unsigned short)(u >> 16);
}
__device__ __forceinline__ float bf2f(unsigned short b) {
    return __uint_as_float(((unsigned)b) << 16);
}

// Block = 16 batch cols, 8 waves (512 thr).
//  W0-3: layer0, tiles {2w, 2w+1};  W4-7: layer1 (lagged 1 step), same tiles.
// MIXED-GATE tiles: tile q covers j in [4q,4q+4); tile-row = 4*jj + gate.
// Lane (col=lane&15, kq=lane>>4) gets D rows = all 4 gates of j = 4*tile+kq
// -> NL fully lane-local. fp32 accuracy: bf16 hi/lo split (3 MFMAs / tile).
// NL uses raw v_rcp/v_exp (R5 was IEEE-divide-sequence-bound in the NL).
__global__ __launch_bounds__(512, 1)
void lstm2_mfma(const float* __restrict__ x,
                const float* __restrict__ w_ih0,
                const float* __restrict__ w_hh0,
                const float* __restrict__ b_ih0,
                const float* __restrict__ b_hh0,
                const float* __restrict__ w_ih1,
                const float* __restrict__ w_hh1,
                const float* __restrict__ b_ih1,
                const float* __restrict__ b_hh1,
                const float* __restrict__ fc1_w,
                const float* __restrict__ fc1_b,
                const float* __restrict__ fc2_w,
                const float* __restrict__ fc2_b,
                float* __restrict__ out)
{
    __shared__ float x_lds[16][XSTR];
    __shared__ unsigned short h0b[2][2][16][HSTR];  // [dbuf][hi/lo][b][k]
    __shared__ unsigned short h1b[2][2][16][HSTR];
    __shared__ float h1f[16][36];                   // final h1 (f32) for head

    const int tid  = threadIdx.x;
    const int wid  = tid >> 6;
    const int lane = tid & 63;
    const int col  = lane & 15;   // batch col
    const int kq   = lane >> 4;
    const int b0   = blockIdx.x * 16;

    // ---- stage x (coalesced float4) ----
    for (int i4 = tid; i4 < (16 * TLEN) / 4; i4 += 512) {
        const int idx = i4 * 4;
        const int row = idx >> 9, cx = idx & 511;
        float4 v = *(const float4*)(x + (long)(b0 + row) * TLEN + cx);
        *(float4*)&x_lds[row][cx] = v;
    }
    for (int i = tid; i < 2 * 2 * 16 * HSTR; i += 512) {
        ((unsigned short*)h0b)[i] = 0;
        ((unsigned short*)h1b)[i] = 0;
    }

    const bool L0    = (wid < 4);
    const int  w4    = wid & 3;
    const int  tile0 = 2 * w4;
    const int  tile1 = 2 * w4 + 1;
    const int  j0    = 4 * tile0 + kq;
    const int  j1    = 4 * tile1 + kq;
    const int  k0    = kq * 8;

    // A-frag weight rows (mixed-gate tile ordering)
    const int arow0 = (col & 3) * 32 + 4 * tile0 + (col >> 2);
    const int arow1 = (col & 3) * 32 + 4 * tile1 + (col >> 2);

    const float* WA = L0 ? w_hh0 : w_ih1;
    bf16x8 wA0hi, wA0lo, wA1hi, wA1lo;
    bf16x8 wB0hi, wB0lo, wB1hi, wB1lo;
    #pragma unroll
    for (int e = 0; e < 8; ++e) {
        float w;
        unsigned short hb;
        w = WA[arow0 * 32 + k0 + e]; hb = f2bf(w);
        wA0hi[e] = (short)hb; wA0lo[e] = (short)f2bf(w - bf2f(hb));
        w = WA[arow1 * 32 + k0 + e]; hb = f2bf(w);
        wA1hi[e] = (short)hb; wA1lo[e] = (short)f2bf(w - bf2f(hb));
        w = L0 ? 0.0f : w_hh1[arow0 * 32 + k0 + e]; hb = f2bf(w);
        wB0hi[e] = (short)hb; wB0lo[e] = (short)f2bf(w - bf2f(hb));
        w = L0 ? 0.0f : w_hh1[arow1 * 32 + k0 + e]; hb = f2bf(w);
        wB1hi[e] = (short)hb; wB1lo[e] = (short)f2bf(w - bf2f(hb));
    }

    // bias / x-weight for this lane's D rows: row(r) = r*32 + 4*tile + kq
    f32x4 bias0, bias1, xw0v, xw1v;
    #pragma unroll
    for (int r = 0; r < 4; ++r) {
        const int r0 = r * 32 + 4 * tile0 + kq;
        const int r1 = r * 32 + 4 * tile1 + kq;
        bias0[r] = L0 ? (b_ih0[r0] + b_hh0[r0]) : (b_ih1[r0] + b_hh1[r0]);
        bias1[r] = L0 ? (b_ih0[r1] + b_hh0[r1]) : (b_ih1[r1] + b_hh1[r1]);
        xw0v[r]  = L0 ? w_ih0[r0] : 0.0f;
        xw1v[r]  = L0 ? w_ih0[r1] : 0.0f;
    }

    float c0_ = 0.0f, c1_ = 0.0f;
    __syncthreads();

// One timestep; CUR/PRV are compile-time literals at every expansion, so all
// LDS addresses fold to base+immediate (no per-step buffer-select VALU).
#define STEP_BODY(T, CUR, PRV)                                                   \
    do {                                                                         \
        const int t_ = (T);                                                      \
        if (L0) {                                                                \
            if (t_ < TLEN) {                                                     \
                const bf16x8 bhi = *(const bf16x8*)&h0b[PRV][0][col][k0];        \
                const bf16x8 blo = *(const bf16x8*)&h0b[PRV][1][col][k0];        \
                const float  xt  = x_lds[col][t_];                               \
                f32x4 a0 = bias0 + xw0v * xt;                                    \
                f32x4 a1 = bias1 + xw1v * xt;                                    \
                a0 = __builtin_amdgcn_mfma_f32_16x16x32_bf16(wA0hi, bhi, a0, 0, 0, 0); \
                a1 = __builtin_amdgcn_mfma_f32_16x16x32_bf16(wA1hi, bhi, a1, 0, 0, 0); \
                a0 = __builtin_amdgcn_mfma_f32_16x16x32_bf16(wA0hi, blo, a0, 0, 0, 0); \
                a1 = __builtin_amdgcn_mfma_f32_16x16x32_bf16(wA1hi, blo, a1, 0, 0, 0); \
                a0 = __builtin_amdgcn_mfma_f32_16x16x32_bf16(wA0lo, bhi, a0, 0, 0, 0); \
                a1 = __builtin_amdgcn_mfma_f32_16x16x32_bf16(wA1lo, bhi, a1, 0, 0, 0); \
                {                                                                \
                    const float iv = sigmoidf_(a0[0]), fv = sigmoidf_(a0[1]);    \
                    const float gv = tanhf_(a0[2]),    ov = sigmoidf_(a0[3]);    \
                    c0_ = fv * c0_ + iv * gv;                                    \
                    const float hv = ov * tanhf_(c0_);                           \
                    const unsigned u = __float_as_uint(hv);                      \
                    h0b[CUR][0][col][j0] = (unsigned short)(u >> 16);            \
                    const float lof = hv - __uint_as_float(u & 0xFFFF0000u);     \
                    h0b[CUR][1][col][j0] = (unsigned short)(__float_as_uint(lof) >> 16); \
                }                                                                \
                {                                                                \
                    const float iv = sigmoidf_(a1[0]), fv = sigmoidf_(a1[1]);    \
                    const float gv = tanhf_(a1[2]),    ov = sigmoidf_(a1[3]);    \
                    c1_ = fv * c1_ + iv * gv;                                    \
                    const float hv = ov * tanhf_(c1_);                           \
                    const unsigned u = __float_as_uint(hv);                      \
                    h0b[CUR][0][col][j1] = (unsigned short)(u >> 16);            \
                    const float lof = hv - __uint_as_float(u & 0xFFFF0000u);     \
                    h0b[CUR][1][col][j1] = (unsigned short)(__float_as_uint(lof) >> 16); \
                }                                                                \
            }                                                                    \
        } else {                                                                 \
            if (t_ >= 1) {                                                       \
                const bf16x8 a0hi = *(const bf16x8*)&h0b[PRV][0][col][k0];       \
                const bf16x8 a0lo = *(const bf16x8*)&h0b[PRV][1][col][k0];       \
                const bf16x8 a1hi = *(const bf16x8*)&h1b[CUR][0][col][k0];       \
                const bf16x8 a1lo = *(const bf16x8*)&h1b[CUR][1][col][k0];       \
                f32x4 a0 = bias0;                                                \
                f32x4 a1 = bias1;                                                \
                a0 = __builtin_amdgcn_mfma_f32_16x16x32_bf16(wA0hi, a0hi, a0, 0, 0, 0); \
                a1 = __builtin_amdgcn_mfma_f32_16x16x32_bf16(wA1hi, a0hi, a1, 0, 0, 0); \
                a0 = __builtin_amdgcn_mfma_f32_16x16x32_bf16(wA0hi, a0lo, a0, 0, 0, 0); \
                a1 = __builtin_amdgcn_mfma_f32_16x16x32_bf16(wA1hi, a0lo, a1, 0, 0, 0); \
                a0 = __builtin_amdgcn_mfma_f32_16x16x32_bf16(wA0lo, a0hi, a0, 0, 0, 0); \
                a1 = __builtin_amdgcn_mfma_f32_16x16x32_bf16(wA1lo, a0hi, a1, 0, 0, 0); \
                a0 = __builtin_amdgcn_mfma_f32_16x16x32_bf16(wB0hi, a1hi, a0, 0, 0, 0); \
                a1 = __builtin_amdgcn_mfma_f32_16x16x32_bf16(wB1hi, a1hi, a1, 0, 0, 0); \
                a0 = __builtin_amdgcn_mfma_f32_16x16x32_bf16(wB0hi, a1lo, a0, 0, 0, 0); \
                a1 = __builtin_amdgcn_mfma_f32_16x16x32_bf16(wB1hi, a1lo, a1, 0, 0, 0); \
                a0 = __builtin_amdgcn_mfma_f32_16x16x32_bf16(wB0lo, a1hi, a0, 0, 0, 0); \
                a1 = __builtin_amdgcn_mfma_f32_16x16x32_bf16(wB1lo, a1hi, a1, 0, 0, 0); \
                float hv0f, hv1f;                                                \
                {                                                                \
                    const float iv = sigmoidf_(a0[0]), fv = sigmoidf_(a0[1]);    \
                    const float gv = tanhf_(a0[2]),    ov = sigmoidf_(a0[3]);    \
                    c0_ = fv * c0_ + iv * gv;                                    \
                    const float hv = ov * tanhf_(c0_);                           \
                    hv0f = hv;                                                   \
                    const unsigned u = __float_as_uint(hv);                      \
                    h1b[PRV][0][col][j0] = (unsigned short)(u >> 16);            \
                    const float lof = hv - __uint_as_float(u & 0xFFFF0000u);     \
                    h1b[PRV][1][col][j0] = (unsigned short)(__float_as_uint(lof) >> 16); \
                }                                                                \
                {                                                                \
                    const float iv = sigmoidf_(a1[0]), fv = sigmoidf_(a1[1]);    \
                    const float gv = tanhf_(a1[2]),    ov = sigmoidf_(a1[3]);    \
                    c1_ = fv * c1_ + iv * gv;                                    \
                    const float hv = ov * tanhf_(c1_);                           \
                    hv1f = hv;                                                   \
                    const unsigned u = __float_as_uint(hv);                      \
                    h1b[PRV][0][col][j1] = (unsigned short)(u >> 16);            \
                    const float lof = hv - __uint_as_float(u & 0xFFFF0000u);     \
                    h1b[PRV][1][col][j1] = (unsigned short)(__float_as_uint(lof) >> 16); \
                }                                                                \
                if (t_ == TLEN) { h1f[col][j0] = hv0f; h1f[col][j1] = hv1f; }    \
            }                                                                    \
        }                                                                        \
        __syncthreads();                                                         \
    } while (0)

    STEP_BODY(0, 0, 1);
    for (int tt = 1; tt < TLEN; tt += 2) {
        STEP_BODY(tt,     1, 0);
        STEP_BODY(tt + 1, 0, 1);
    }
#undef STEP_BODY

    // ---- head: out[b] = fc2( relu( fc1 . h1_T ) ) + fc2_b, by wave 0 ----
    if (wid == 0) {
        float s = 0.0f;
        #pragma unroll
        for (int it = 0; it < 4; ++it) {
            const int r = kq * 4 + it;    // fc1 row in [0,16)
            float acc = fc1_b[r];
            #pragma unroll
            for (int qq = 0; qq < 8; ++qq) {
                const float4 wv = *(const float4*)(fc1_w + r * 32 + qq * 4);
                const float4 hv = *(const float4*)&h1f[col][qq * 4];
                acc += wv.x * hv.x + wv.y * hv.y + wv.z * hv.z + wv.w * hv.w;
            }
            s += fmaxf(acc, 0.0f) * fc2_w[r];
        }
        s += __shfl_xor(s, 16);
        s += __shfl_xor(s, 32);
        if (lane < 16) out[b0 + col] = s + fc2_b[0];
    }
}

extern "C" void kernel_launch(void* const* d_in, const int* in_sizes, int n_in,
                              void* d_out, int out_size, void* d_ws, size_t ws_size,
                              hipStream_t stream) {
    const float* x     = (const float*)d_in[0];
    const float* w_ih0 = (const float*)d_in[1];
    const float* w_hh0 = (const float*)d_in[2];
    const float* b_ih0 = (const float*)d_in[3];
    const float* b_hh0 = (const float*)d_in[4];
    const float* w_ih1 = (const float*)d_in[5];
    const float* w_hh1 = (const float*)d_in[6];
    const float* b_ih1 = (const float*)d_in[7];
    const float* b_hh1 = (const float*)d_in[8];
    const float* fc1_w = (const float*)d_in[9];
    const float* fc1_b = (const float*)d_in[10];
    const float* fc2_w = (const float*)d_in[11];
    const float* fc2_b = (const float*)d_in[12];
    float* out = (float*)d_out;

    dim3 grid(4096 / 16);   // 256 blocks, 1 per CU
    dim3 block(512);        // 8 waves -> 2 per SIMD
    hipLaunchKernelGGL(lstm2_mfma, grid, block, 0, stream,
                       x, w_ih0, w_hh0, b_ih0, b_hh0,
                       w_ih1, w_hh1, b_ih1, b_hh1,
                       fc1_w, fc1_b, fc2_w, fc2_b, out);
}

// Round 7
// 235.451 us; speedup vs baseline: 6.4654x; 1.0496x over previous
//
#include <hip/hip_runtime.h>

#define TLEN 512
#define XSTR 516      // x LDS row stride (floats)
#define HSTR 40       // h LDS row stride (bf16 elems): 80B rows, 16B-aligned frags

typedef __attribute__((ext_vector_type(8))) short bf16x8;
typedef __attribute__((ext_vector_type(4))) float f32x4;

#define LOG2E_ 1.44269504f
#define S2F_   2.88539008f   // 2*log2e; c kept in S2F*c space

__device__ __forceinline__ float fexp2_(float x) {
#if __has_builtin(__builtin_amdgcn_exp2f)
    return __builtin_amdgcn_exp2f(x);      // raw v_exp_f32
#else
    return __expf(x * 0.69314718056f);
#endif
}
__device__ __forceinline__ float frcp_(float x) {
#if __has_builtin(__builtin_amdgcn_rcpf)
    return __builtin_amdgcn_rcpf(x);       // raw v_rcp_f32 (~1 ulp)
#else
    return 1.0f / x;
#endif
}
__device__ __forceinline__ unsigned short f2bf(float f) {   // RNE (setup only)
    unsigned u = __float_as_uint(f);
    u += 0x7FFFu + ((u >> 16) & 1u);
    return (unsigned short)(u >> 16);
}
__device__ __forceinline__ float bf2f(unsigned short b) {
    return __uint_as_float(((unsigned)b) << 16);
}

// Gate pre-activations arrive PRE-SCALED (weights/biases folded):
//  sigmoid rows (i,f,o): a = -log2e * x  -> sig = rcp(1+exp2(a))
//  tanh row    (g):      a = 2log2e * x  -> S2F*tanh = S2F - 2*S2F*rcp(1+exp2(a))
// c state kept in S2F*c space -> tanh(c) = 1 - 2*rcp(1+exp2(c')).
__device__ __forceinline__ float lstm_nl(const f32x4 a, float& cS) {
    const float i_ = frcp_(1.0f + fexp2_(a[0]));
    const float f_ = frcp_(1.0f + fexp2_(a[1]));
    const float rg = frcp_(1.0f + fexp2_(a[2]));
    const float g_ = S2F_ - 2.0f * S2F_ * rg;      // S2F*tanh(g)
    const float o_ = frcp_(1.0f + fexp2_(a[3]));
    cS = f_ * cS + i_ * g_;
    const float rc = frcp_(1.0f + fexp2_(cS));
    return o_ * (1.0f - 2.0f * rc);
}

// Block = 16 batch cols, 8 waves (512 thr). BALANCED: wave w owns tile w of
// BOTH layers (L0: 3 MFMAs, L1: 6 MFMAs = 9 each), so no straggler at the
// per-step barrier (R6 had L0=6 vs L1=12 across separate waves).
// MIXED-GATE tiles: tile-row tr = 4*jj + gate; weight row = gate*32+4*tile+jj.
// Lane (col=lane&15, kq=lane>>4): D rows kq*4+r = all 4 gates of j=4*tile+kq.
// fp32 accuracy: bf16 hi/lo split, 3 MFMAs per matvec.
// L1 lags L0 by one step; both parts read only prev-parity buffers ->
// independent within a step, one barrier per step, shared h0[prv] frags.
__global__ __launch_bounds__(512, 1)
void lstm2_mfma(const float* __restrict__ x,
                const float* __restrict__ w_ih0,
                const float* __restrict__ w_hh0,
                const float* __restrict__ b_ih0,
                const float* __restrict__ b_hh0,
                const float* __restrict__ w_ih1,
                const float* __restrict__ w_hh1,
                const float* __restrict__ b_ih1,
                const float* __restrict__ b_hh1,
                const float* __restrict__ fc1_w,
                const float* __restrict__ fc1_b,
                const float* __restrict__ fc2_w,
                const float* __restrict__ fc2_b,
                float* __restrict__ out)
{
    __shared__ float x_lds[16][XSTR];
    __shared__ unsigned short h0b[2][2][16][HSTR];  // [dbuf][hi/lo][b][k]
    __shared__ unsigned short h1b[2][2][16][HSTR];
    __shared__ float h1f[16][36];                   // final h1 (f32) for head

    const int tid  = threadIdx.x;
    const int wid  = tid >> 6;    // = tile index (0..7)
    const int lane = tid & 63;
    const int col  = lane & 15;   // batch col
    const int kq   = lane >> 4;
    const int b0   = blockIdx.x * 16;

    // ---- stage x (coalesced float4) ----
    for (int i4 = tid; i4 < (16 * TLEN) / 4; i4 += 512) {
        const int idx = i4 * 4;
        const int row = idx >> 9, cx = idx & 511;
        float4 v = *(const float4*)(x + (long)(b0 + row) * TLEN + cx);
        *(float4*)&x_lds[row][cx] = v;
    }
    for (int i = tid; i < 2 * 2 * 16 * HSTR; i += 512) {
        ((unsigned short*)h0b)[i] = 0;
        ((unsigned short*)h1b)[i] = 0;
    }

    const int tile = wid;
    const int jj   = 4 * tile + kq;    // this lane's j (both layers)
    const int k0   = kq * 8;

    // A-frag weight row (mixed-gate tile ordering); per-row exp2 pre-scale
    const int   arow = (col & 3) * 32 + 4 * tile + (col >> 2);
    const float sA   = ((col & 3) == 2) ? S2F_ : -LOG2E_;

    bf16x8 wL0hi, wL0lo, wIhi, wIlo, wHhi, wHlo;
    #pragma unroll
    for (int e = 0; e < 8; ++e) {
        float w;
        unsigned short hb;
        w = sA * w_hh0[arow * 32 + k0 + e]; hb = f2bf(w);
        wL0hi[e] = (short)hb; wL0lo[e] = (short)f2bf(w - bf2f(hb));
        w = sA * w_ih1[arow * 32 + k0 + e]; hb = f2bf(w);
        wIhi[e]  = (short)hb; wIlo[e]  = (short)f2bf(w - bf2f(hb));
        w = sA * w_hh1[arow * 32 + k0 + e]; hb = f2bf(w);
        wHhi[e]  = (short)hb; wHlo[e]  = (short)f2bf(w - bf2f(hb));
    }

    // bias / x-weight for this lane's D rows: row(r) = r*32 + 4*tile + kq
    f32x4 biasL0, biasL1, xwv;
    #pragma unroll
    for (int r = 0; r < 4; ++r) {
        const int  row = r * 32 + 4 * tile + kq;
        const float sr = (r == 2) ? S2F_ : -LOG2E_;
        biasL0[r] = sr * (b_ih0[row] + b_hh0[row]);
        biasL1[r] = sr * (b_ih1[row] + b_hh1[row]);
        xwv[r]    = sr * w_ih0[row];
    }

    float cL0 = 0.0f, cL1 = 0.0f;     // cell states (S2F-scaled)
    __syncthreads();

#define PACK_H(BUF, PAR, HV, J)                                                  \
    do {                                                                         \
        const unsigned u_ = __float_as_uint(HV);                                 \
        BUF[PAR][0][col][J] = (unsigned short)(u_ >> 16);                        \
        const float lof_ = (HV) - __uint_as_float(u_ & 0xFFFF0000u);             \
        BUF[PAR][1][col][J] = (unsigned short)(__float_as_uint(lof_) >> 16);     \
    } while (0)

// One timestep; CUR/PRV compile-time -> LDS addrs fold to base+immediate.
#define STEP_BODY(T, CUR, PRV)                                                   \
    do {                                                                         \
        const int t_ = (T);                                                      \
        const bf16x8 bhi = *(const bf16x8*)&h0b[PRV][0][col][k0];                \
        const bf16x8 blo = *(const bf16x8*)&h0b[PRV][1][col][k0];                \
        if (t_ < TLEN) {                                                         \
            const float xt = x_lds[col][t_];                                     \
            f32x4 aL0 = biasL0 + xwv * xt;                                       \
            aL0 = __builtin_amdgcn_mfma_f32_16x16x32_bf16(wL0hi, bhi, aL0, 0, 0, 0); \
            aL0 = __builtin_amdgcn_mfma_f32_16x16x32_bf16(wL0hi, blo, aL0, 0, 0, 0); \
            aL0 = __builtin_amdgcn_mfma_f32_16x16x32_bf16(wL0lo, bhi, aL0, 0, 0, 0); \
            const float hv = lstm_nl(aL0, cL0);                                  \
            PACK_H(h0b, CUR, hv, jj);                                            \
        }                                                                        \
        if (t_ >= 1) {                                                           \
            const bf16x8 chi = *(const bf16x8*)&h1b[CUR][0][col][k0];            \
            const bf16x8 clo = *(const bf16x8*)&h1b[CUR][1][col][k0];            \
            f32x4 aL1 = biasL1;                                                  \
            aL1 = __builtin_amdgcn_mfma_f32_16x16x32_bf16(wIhi, bhi, aL1, 0, 0, 0); \
            aL1 = __builtin_amdgcn_mfma_f32_16x16x32_bf16(wIhi, blo, aL1, 0, 0, 0); \
            aL1 = __builtin_amdgcn_mfma_f32_16x16x32_bf16(wIlo, bhi, aL1, 0, 0, 0); \
            aL1 = __builtin_amdgcn_mfma_f32_16x16x32_bf16(wHhi, chi, aL1, 0, 0, 0); \
            aL1 = __builtin_amdgcn_mfma_f32_16x16x32_bf16(wHhi, clo, aL1, 0, 0, 0); \
            aL1 = __builtin_amdgcn_mfma_f32_16x16x32_bf16(wHlo, chi, aL1, 0, 0, 0); \
            const float hv = lstm_nl(aL1, cL1);                                  \
            PACK_H(h1b, PRV, hv, jj);                                            \
            if (t_ == TLEN) h1f[col][jj] = hv;                                   \
        }                                                                        \
        __syncthreads();                                                         \
    } while (0)

    STEP_BODY(0, 0, 1);
    for (int tt = 1; tt < TLEN; tt += 2) {
        STEP_BODY(tt,     1, 0);
        STEP_BODY(tt + 1, 0, 1);
    }
#undef STEP_BODY
#undef PACK_H

    // ---- head: out[b] = fc2( relu( fc1 . h1_T ) ) + fc2_b, by wave 0 ----
    if (wid == 0) {
        float s = 0.0f;
        #pragma unroll
        for (int it = 0; it < 4; ++it) {
            const int r = kq * 4 + it;    // fc1 row in [0,16)
            float acc = fc1_b[r];
            #pragma unroll
            for (int qq = 0; qq < 8; ++qq) {
                const float4 wv = *(const float4*)(fc1_w + r * 32 + qq * 4);
                const float4 hv = *(const float4*)&h1f[col][qq * 4];
                acc += wv.x * hv.x + wv.y * hv.y + wv.z * hv.z + wv.w * hv.w;
            }
            s += fmaxf(acc, 0.0f) * fc2_w[r];
        }
        s += __shfl_xor(s, 16);
        s += __shfl_xor(s, 32);
        if (lane < 16) out[b0 + col] = s + fc2_b[0];
    }
}

extern "C" void kernel_launch(void* const* d_in, const int* in_sizes, int n_in,
                              void* d_out, int out_size, void* d_ws, size_t ws_size,
                              hipStream_t stream) {
    const float* x     = (const float*)d_in[0];
    const float* w_ih0 = (const float*)d_in[1];
    const float* w_hh0 = (const float*)d_in[2];
    const float* b_ih0 = (const float*)d_in[3];
    const float* b_hh0 = (const float*)d_in[4];
    const float* w_ih1 = (const float*)d_in[5];
    const float* w_hh1 = (const float*)d_in[6];
    const float* b_ih1 = (const float*)d_in[7];
    const float* b_hh1 = (const float*)d_in[8];
    const float* fc1_w = (const float*)d_in[9];
    const float* fc1_b = (const float*)d_in[10];
    const float* fc2_w = (const float*)d_in[11];
    const float* fc2_b = (const float*)d_in[12];
    float* out = (float*)d_out;

    dim3 grid(4096 / 16);   // 256 blocks, 1 per CU
    dim3 block(512);        // 8 balanced waves -> 2 per SIMD
    hipLaunchKernelGGL(lstm2_mfma, grid, block, 0, stream,
                       x, w_ih0, w_hh0, b_ih0, b_hh0,
                       w_ih1, w_hh1, b_ih1, b_hh1,
                       fc1_w, fc1_b, fc2_w, fc2_b, out);
}